// Round 3
// baseline (261.559 us; speedup 1.0000x reference)
//
#include <hip/hip_runtime.h>

// Problem constants
#define SRC_N   (512 * 512)        // gaussians per batch = 262144
#define IMG_W   1024
#define IMG_HW  (1024 * 1024)
#define BATCH   4

// Mode A (interleaved staging) constants
#define SLOTS    4096                          // boundary slots per (b): top|bottom|left|right
#define STAGE_F4 ((size_t)BATCH * IMG_HW)      // 4M float4 = 64 MB
#define REPL_F4  ((size_t)BATCH * SLOTS)       // 16384 float4 = 256 KB per replica

// Mode B constants (R2 fallback layout)
#define BSLOTS  4096
#define BSTRIDE (BATCH * 3 * BSLOTS)

__device__ __forceinline__ float wave_sum64(float v) {
#pragma unroll
    for (int off = 32; off; off >>= 1) v += __shfl_xor(v, off, 64);
    return v;
}

// ---------------------------------------------------------------------------
// MODE A scatter: barrier-free, RGB-interleaved targets (1 dirty line/point).
// Interior -> stage[b][pix] (float4). Edge -> replica float4 slots.
// Corner -> per-wave shuffle reduction, 12 atomics/wave to replica slots.
// ---------------------------------------------------------------------------
__global__ void __launch_bounds__(256)
scatter_a(const float* __restrict__ uv,
          const float* __restrict__ pos,
          float* __restrict__ stage,
          float* __restrict__ repl,
          int rmask) {
    const int gid = blockIdx.x * blockDim.x + threadIdx.x;
    const int b = gid >> 18;            // / SRC_N (uniform per block)
    const int n = gid & (SRC_N - 1);

    const float* uvb = uv  + (size_t)b * 14 * SRC_N;
    const float* pb  = pos + (size_t)b * 3  * SRC_N;

    const float posx = pb[n]         + uvb[n];
    const float posy = pb[SRC_N + n] + uvb[SRC_N + n];

    const float o    = uvb[10 * SRC_N + n];
    const float opac = 1.0f / (1.0f + __expf(-o));

    const float r  = uvb[11 * SRC_N + n] * opac;
    const float g  = uvb[12 * SRC_N + n] * opac;
    const float bl = uvb[13 * SRC_N + n] * opac;

    int px = (int)((posx + 1.0f) * 512.0f);   // truncating cast, then clamp
    int py = (int)((posy + 1.0f) * 512.0f);
    px = min(max(px, 0), IMG_W - 1);
    py = min(max(py, 0), IMG_W - 1);

    const bool xe = (px == 0) | (px == IMG_W - 1);
    const bool ye = (py == 0) | (py == IMG_W - 1);
    const bool isc = xe & ye;

    // per-wave replica (spreads consecutive waves across replicas)
    const int ridx = ((blockIdx.x << 2) | (threadIdx.x >> 6)) & rmask;
    float* rb = repl + (size_t)ridx * (REPL_F4 * 4) + (size_t)b * SLOTS * 4;

    if (isc) {
        // handled by wave reduction below
    } else if (ye) {
        const int slot = (py == 0) ? px : (1024 + px);
        float* p = rb + slot * 4;
        atomicAdd(p + 0, r); atomicAdd(p + 1, g); atomicAdd(p + 2, bl);
    } else if (xe) {
        const int slot = (px == 0) ? (2048 + py) : (3072 + py);
        float* p = rb + slot * 4;
        atomicAdd(p + 0, r); atomicAdd(p + 1, g); atomicAdd(p + 2, bl);
    } else {
        float* p = stage + ((size_t)b * IMG_HW + py * IMG_W + px) * 4;
        atomicAdd(p + 0, r); atomicAdd(p + 1, g); atomicAdd(p + 2, bl);
    }

    // corner: 12 masked wave sums (all lanes participate, no divergence)
    const int ci = ((py != 0) ? 2 : 0) + ((px != 0) ? 1 : 0);
    const float s0r = wave_sum64((isc && ci == 0) ? r  : 0.0f);
    const float s0g = wave_sum64((isc && ci == 0) ? g  : 0.0f);
    const float s0b = wave_sum64((isc && ci == 0) ? bl : 0.0f);
    const float s1r = wave_sum64((isc && ci == 1) ? r  : 0.0f);
    const float s1g = wave_sum64((isc && ci == 1) ? g  : 0.0f);
    const float s1b = wave_sum64((isc && ci == 1) ? bl : 0.0f);
    const float s2r = wave_sum64((isc && ci == 2) ? r  : 0.0f);
    const float s2g = wave_sum64((isc && ci == 2) ? g  : 0.0f);
    const float s2b = wave_sum64((isc && ci == 2) ? bl : 0.0f);
    const float s3r = wave_sum64((isc && ci == 3) ? r  : 0.0f);
    const float s3g = wave_sum64((isc && ci == 3) ? g  : 0.0f);
    const float s3b = wave_sum64((isc && ci == 3) ? bl : 0.0f);

    const int l = threadIdx.x & 63;
    if (l < 12) {
        float v;
        if      (l == 0)  v = s0r;
        else if (l == 1)  v = s0g;
        else if (l == 2)  v = s0b;
        else if (l == 3)  v = s1r;
        else if (l == 4)  v = s1g;
        else if (l == 5)  v = s1b;
        else if (l == 6)  v = s2r;
        else if (l == 7)  v = s2g;
        else if (l == 8)  v = s2b;
        else if (l == 9)  v = s3r;
        else if (l == 10) v = s3g;
        else              v = s3b;
        if (v != 0.0f) {
            const int k = l / 3;          // corner id
            const int c = l - k * 3;      // channel
            // corner -> boundary slot: (0,0)->0 (0,1023)->1023 (1023,0)->1024 (1023,1023)->2047
            const int cslot = (k == 0) ? 0 : (k == 1) ? 1023 : (k == 2) ? 1024 : 2047;
            atomicAdd(rb + cslot * 4 + c, v);
        }
    }
}

// Reduce replicas -> boundary pixels, direct float4 store into staging.
__global__ void __launch_bounds__(256)
reduce_a(const float4* __restrict__ repl, float4* __restrict__ stage, int R) {
    const int t = blockIdx.x * blockDim.x + threadIdx.x;
    if (t >= BATCH * SLOTS) return;
    const int b = t >> 12;
    const int e = t & (SLOTS - 1);

    float4 s = make_float4(0.f, 0.f, 0.f, 0.f);
    for (int r = 0; r < R; ++r) {
        float4 v = repl[(size_t)r * REPL_F4 + t];
        s.x += v.x; s.y += v.y; s.z += v.z; s.w += v.w;
    }

    int px, py;
    if (e < 1024)      { py = 0;    px = e; }
    else if (e < 2048) { py = 1023; px = e - 1024; }
    else if (e < 3072) { px = 0;    py = e - 2048; if (py == 0 || py == 1023) return; }
    else               { px = 1023; py = e - 3072; if (py == 0 || py == 1023) return; }

    stage[(size_t)b * IMG_HW + py * IMG_W + px] = s;
}

// Merge: staging (interleaved) -> out planes, with clip. 4 pixels/thread.
__global__ void __launch_bounds__(256)
merge_a(const float4* __restrict__ stage, float* __restrict__ out) {
    const int i = blockIdx.x * blockDim.x + threadIdx.x;   // 1,048,576 threads
    const int b = i >> 18;                                  // 262144 groups/batch
    const int q = i & ((IMG_HW / 4) - 1);

    const float4* sp = stage + (size_t)b * IMG_HW + (size_t)q * 4;
    const float4 s0 = sp[0], s1 = sp[1], s2 = sp[2], s3 = sp[3];

    float4 r4 = make_float4(s0.x, s1.x, s2.x, s3.x);
    float4 g4 = make_float4(s0.y, s1.y, s2.y, s3.y);
    float4 b4 = make_float4(s0.z, s1.z, s2.z, s3.z);
#define CLIP4(v) v.x=fminf(fmaxf(v.x,0.f),1.f); v.y=fminf(fmaxf(v.y,0.f),1.f); \
                 v.z=fminf(fmaxf(v.z,0.f),1.f); v.w=fminf(fmaxf(v.w,0.f),1.f)
    CLIP4(r4); CLIP4(g4); CLIP4(b4);

    float4* ob = (float4*)(out + (size_t)b * 3 * IMG_HW);
    ob[0 * (IMG_HW / 4) + q] = r4;
    ob[1 * (IMG_HW / 4) + q] = g4;
    ob[2 * (IMG_HW / 4) + q] = b4;
}

// ---------------------------------------------------------------------------
// MODE B — R2 fallback (used only if ws is too small for staging).
// ---------------------------------------------------------------------------
__global__ void __launch_bounds__(256)
scatter_b(const float* __restrict__ uv, const float* __restrict__ pos,
          float* __restrict__ out, float* __restrict__ repl, int rmask) {
    const int gid = blockIdx.x * blockDim.x + threadIdx.x;
    const int b = gid >> 18;
    const int n = gid & (SRC_N - 1);

    const float* uvb = uv  + (size_t)b * 14 * SRC_N;
    const float* pb  = pos + (size_t)b * 3  * SRC_N;

    const float posx = pb[n]         + uvb[n];
    const float posy = pb[SRC_N + n] + uvb[SRC_N + n];
    const float o    = uvb[10 * SRC_N + n];
    const float opac = 1.0f / (1.0f + __expf(-o));
    const float r  = uvb[11 * SRC_N + n] * opac;
    const float g  = uvb[12 * SRC_N + n] * opac;
    const float bl = uvb[13 * SRC_N + n] * opac;

    int px = (int)((posx + 1.0f) * 512.0f);
    int py = (int)((posy + 1.0f) * 512.0f);
    px = min(max(px, 0), IMG_W - 1);
    py = min(max(py, 0), IMG_W - 1);

    float* rb = repl + (size_t)(blockIdx.x & rmask) * BSTRIDE + (size_t)b * 3 * BSLOTS;

    __shared__ float sc[12];
    if (threadIdx.x < 12) sc[threadIdx.x] = 0.0f;
    __syncthreads();

    const bool xe = (px == 0) | (px == IMG_W - 1);
    const bool ye = (py == 0) | (py == IMG_W - 1);

    if (xe & ye) {
        const int ci = ((py != 0) ? 2 : 0) + ((px != 0) ? 1 : 0);
        atomicAdd(&sc[ci * 3 + 0], r);
        atomicAdd(&sc[ci * 3 + 1], g);
        atomicAdd(&sc[ci * 3 + 2], bl);
    } else if (ye) {
        const int slot = (py == 0) ? px : (1024 + px);
        atomicAdd(&rb[0 * BSLOTS + slot], r);
        atomicAdd(&rb[1 * BSLOTS + slot], g);
        atomicAdd(&rb[2 * BSLOTS + slot], bl);
    } else if (xe) {
        const int slot = (px == 0) ? (2048 + py) : (3072 + py);
        atomicAdd(&rb[0 * BSLOTS + slot], r);
        atomicAdd(&rb[1 * BSLOTS + slot], g);
        atomicAdd(&rb[2 * BSLOTS + slot], bl);
    } else {
        const size_t ob = (size_t)b * 3 * IMG_HW;
        const int idx = py * IMG_W + px;
        atomicAdd(&out[ob + 0 * IMG_HW + idx], r);
        atomicAdd(&out[ob + 1 * IMG_HW + idx], g);
        atomicAdd(&out[ob + 2 * IMG_HW + idx], bl);
    }
    __syncthreads();

    if (threadIdx.x < 12) {
        const float v = sc[threadIdx.x];
        if (v != 0.0f) {
            const int ci = threadIdx.x / 3;
            const int c  = threadIdx.x % 3;
            const int cslot[4] = {0, 1023, 1024, 2047};
            atomicAdd(&rb[c * BSLOTS + cslot[ci]], v);
        }
    }
}

__global__ void __launch_bounds__(256)
reduce_b(const float* __restrict__ repl, float* __restrict__ out, int R) {
    const int t = blockIdx.x * blockDim.x + threadIdx.x;
    if (t >= BSTRIDE) return;
    float s = 0.0f;
    for (int r = 0; r < R; ++r) s += repl[(size_t)r * BSTRIDE + t];
    const int b   = t / (3 * BSLOTS);
    const int rem = t % (3 * BSLOTS);
    const int c   = rem / BSLOTS;
    const int e   = rem % BSLOTS;
    int px, py;
    if (e < 1024)      { py = 0;    px = e; }
    else if (e < 2048) { py = 1023; px = e - 1024; }
    else if (e < 3072) { px = 0;    py = e - 2048; if (py == 0 || py == 1023) return; }
    else               { px = 1023; py = e - 3072; if (py == 0 || py == 1023) return; }
    out[(size_t)b * 3 * IMG_HW + (size_t)c * IMG_HW + py * IMG_W + px] = s;
}

__global__ void __launch_bounds__(256)
clip_b(float4* __restrict__ out, int n4) {
    const int i = blockIdx.x * blockDim.x + threadIdx.x;
    if (i < n4) {
        float4 v = out[i];
        v.x = fminf(fmaxf(v.x, 0.0f), 1.0f);
        v.y = fminf(fmaxf(v.y, 0.0f), 1.0f);
        v.z = fminf(fmaxf(v.z, 0.0f), 1.0f);
        v.w = fminf(fmaxf(v.w, 0.0f), 1.0f);
        out[i] = v;
    }
}

extern "C" void kernel_launch(void* const* d_in, const int* in_sizes, int n_in,
                              void* d_out, int out_size, void* d_ws, size_t ws_size,
                              hipStream_t stream) {
    const float* uv  = (const float*)d_in[0];   // (4,14,512,512)
    const float* pos = (const float*)d_in[1];   // (4,3,512,512)
    float* out = (float*)d_out;                 // (4,3,1024,1024)

    const size_t stage_bytes = STAGE_F4 * sizeof(float4);      // 64 MB
    const size_t replA_bytes = REPL_F4 * sizeof(float4);       // 256 KB

    if (ws_size >= stage_bytes + 8 * replA_bytes) {
        // ---- MODE A ----
        int R = 8;
        while (R * 2 <= 64 && stage_bytes + (size_t)(R * 2) * replA_bytes <= ws_size) R *= 2;
        float* stage = (float*)d_ws;
        float* repl  = (float*)((char*)d_ws + stage_bytes);

        hipMemsetAsync(d_ws, 0, stage_bytes + (size_t)R * replA_bytes, stream);

        scatter_a<<<(BATCH * SRC_N) / 256, 256, 0, stream>>>(uv, pos, stage, repl, R - 1);
        reduce_a<<<(BATCH * SLOTS + 255) / 256, 256, 0, stream>>>(
            (const float4*)repl, (float4*)stage, R);
        merge_a<<<(BATCH * IMG_HW / 4) / 256, 256, 0, stream>>>((const float4*)stage, out);
    } else {
        // ---- MODE B (R2 fallback) ----
        const size_t replB_bytes = (size_t)BSTRIDE * sizeof(float);
        int R = 1;
        while (R * 2 <= 64 && (size_t)(R * 2) * replB_bytes <= ws_size) R *= 2;
        float* repl = (float*)d_ws;

        hipMemsetAsync(d_out, 0, (size_t)out_size * sizeof(float), stream);
        hipMemsetAsync(d_ws, 0, (size_t)R * replB_bytes, stream);

        scatter_b<<<(BATCH * SRC_N) / 256, 256, 0, stream>>>(uv, pos, out, repl, R - 1);
        reduce_b<<<(BSTRIDE + 255) / 256, 256, 0, stream>>>(repl, out, R);
        const int n4 = out_size / 4;
        clip_b<<<(n4 + 255) / 256, 256, 0, stream>>>((float4*)out, n4);
    }
}

// Round 4
// 163.849 us; speedup vs baseline: 1.5963x; 1.5963x over previous
//
#include <hip/hip_runtime.h>

// Problem constants
#define SRC_N   (512 * 512)        // gaussians per batch = 262144
#define IMG_W   1024
#define IMG_HW  (1024 * 1024)
#define BATCH   4

#define K1_BLOCKS      256         // 64 blocks per batch
#define PTS_PER_BLOCK  4096
#define NBINS          256         // per batch: 16x16 tiles of 64x64 pixels
#define SENT           0xFFFFFFFFu

// ws layout (bytes)
#define PAYLOAD_BYTES  ((size_t)K1_BLOCKS * PTS_PER_BLOCK * 16)        // 16 MB
#define PREFIX_OFF     PAYLOAD_BYTES
#define PREFIX_N       (K1_BLOCKS * (NBINS + 1))                       // 65792 u32
#define CORNER_OFF     (PREFIX_OFF + (((size_t)PREFIX_N * 4 + 255) & ~(size_t)255))
// corner_out: [K1_BLOCKS][12] floats (plain stores, no memset needed)

// ---------------------------------------------------------------------------
// K1: classify + bin. Each block: private LDS histogram over 256 bins,
// LDS scan, per-block prefix table -> ws, payload scatter into the block's
// PRIVATE 64KB region (LDS cursors). Corners -> 12-float LDS accumulator ->
// plain per-block store. ZERO global atomics.
// ---------------------------------------------------------------------------
__global__ void __launch_bounds__(1024)
bin_kernel(const float* __restrict__ uv, const float* __restrict__ pos,
           float4* __restrict__ payload, unsigned* __restrict__ prefix,
           float* __restrict__ corner_out) {
    const int blk   = blockIdx.x;          // 0..255
    const int b     = blk >> 6;            // batch (uniform per block)
    const int chunk = blk & 63;
    const int t     = threadIdx.x;

    __shared__ unsigned s_hist[NBINS];
    __shared__ unsigned s_scan[NBINS];
    __shared__ unsigned s_cur[NBINS];
    __shared__ float    s_corner[12];

    if (t < NBINS) s_hist[t] = 0;
    if (t < 12)    s_corner[t] = 0.0f;
    __syncthreads();

    const float* uvb = uv  + (size_t)b * 14 * SRC_N;
    const float* pb  = pos + (size_t)b * 3  * SRC_N;
    const int n0 = chunk * PTS_PER_BLOCK + t * 4;   // 16B-aligned

    // vectorized channel reads: 4 consecutive points per thread
    const float4 pxv = *(const float4*)&pb [n0];
    const float4 pyv = *(const float4*)&pb [SRC_N + n0];
    const float4 ux  = *(const float4*)&uvb[n0];
    const float4 uy  = *(const float4*)&uvb[SRC_N + n0];
    const float4 ov  = *(const float4*)&uvb[10 * SRC_N + n0];
    const float4 rv  = *(const float4*)&uvb[11 * SRC_N + n0];
    const float4 gv  = *(const float4*)&uvb[12 * SRC_N + n0];
    const float4 bv  = *(const float4*)&uvb[13 * SRC_N + n0];

    const float X[4] = {pxv.x + ux.x, pxv.y + ux.y, pxv.z + ux.z, pxv.w + ux.w};
    const float Y[4] = {pyv.x + uy.x, pyv.y + uy.y, pyv.z + uy.z, pyv.w + uy.w};
    const float O[4] = {ov.x, ov.y, ov.z, ov.w};
    const float CR[4] = {rv.x, rv.y, rv.z, rv.w};
    const float CG[4] = {gv.x, gv.y, gv.z, gv.w};
    const float CB[4] = {bv.x, bv.y, bv.z, bv.w};

    unsigned packed[4];
    float R[4], G[4], B[4];

#pragma unroll
    for (int j = 0; j < 4; ++j) {
        // truncating cast (matches .astype(int32)), then clamp; x0.5 and x1024
        // are exact powers of two so (x+1)*512 == ((x+1)*0.5)*1024 bit-exactly
        int px = (int)((X[j] + 1.0f) * 512.0f);
        int py = (int)((Y[j] + 1.0f) * 512.0f);
        px = min(max(px, 0), IMG_W - 1);
        py = min(max(py, 0), IMG_W - 1);

        const float opac = 1.0f / (1.0f + __expf(-O[j]));
        const float r  = CR[j] * opac;
        const float g  = CG[j] * opac;
        const float bl = CB[j] * opac;
        R[j] = r; G[j] = g; B[j] = bl;

        const bool xe = (px == 0) | (px == IMG_W - 1);
        const bool ye = (py == 0) | (py == IMG_W - 1);
        if (xe & ye) {
            const int ci = ((py != 0) ? 2 : 0) + ((px != 0) ? 1 : 0);
            atomicAdd(&s_corner[ci * 3 + 0], r);
            atomicAdd(&s_corner[ci * 3 + 1], g);
            atomicAdd(&s_corner[ci * 3 + 2], bl);
            packed[j] = SENT;
        } else {
            const int bin = ((py >> 6) << 4) | (px >> 6);    // 0..255
            atomicAdd(&s_hist[bin], 1u);
            packed[j] = ((unsigned)bin << 12) | ((unsigned)(py & 63) << 6)
                      | (unsigned)(px & 63);
        }
    }
    __syncthreads();

    // inclusive scan of s_hist into s_scan (Hillis-Steele, uniform barriers)
    if (t < NBINS) s_scan[t] = s_hist[t];
    __syncthreads();
    for (int d = 1; d < NBINS; d <<= 1) {
        unsigned v = 0;
        if (t < NBINS && t >= d) v = s_scan[t - d];
        __syncthreads();
        if (t < NBINS) s_scan[t] += v;
        __syncthreads();
    }

    // exclusive prefix -> cursors + global prefix table
    if (t < NBINS) {
        const unsigned excl = s_scan[t] - s_hist[t];
        s_cur[t] = excl;
        prefix[blk * (NBINS + 1) + t] = excl;
    }
    if (t == 0) prefix[blk * (NBINS + 1) + NBINS] = s_scan[NBINS - 1];
    if (t < 12) corner_out[blk * 12 + t] = s_corner[t];   // plain store
    __syncthreads();

    // payload scatter into the block's private region
    float4* pbase = payload + (size_t)blk * PTS_PER_BLOCK;
#pragma unroll
    for (int j = 0; j < 4; ++j) {
        if (packed[j] != SENT) {
            const int bin = packed[j] >> 12;
            const unsigned p = atomicAdd(&s_cur[bin], 1u);
            pbase[p] = make_float4(__uint_as_float(packed[j] & 0xFFFu),
                                   R[j], G[j], B[j]);
        }
    }
}

// ---------------------------------------------------------------------------
// K2: one block per (batch, 64x64 tile). Gather the tile's payload runs from
// the 64 source blocks of its batch, accumulate in a 48KB LDS sub-image
// (LDS atomics; max per-pixel depth ~35 on edges), fold corner partials,
// then dense clipped stores (every output pixel written exactly once).
// ---------------------------------------------------------------------------
__global__ void __launch_bounds__(1024)
accum_kernel(const float4* __restrict__ payload, const unsigned* __restrict__ prefix,
             const float* __restrict__ corner_out, float* __restrict__ out) {
    const int bg   = blockIdx.x;           // 0..1023
    const int b    = bg >> 8;
    const int tile = bg & 255;
    const int ty   = tile >> 4, tx = tile & 15;
    const int t    = threadIdx.x;

    __shared__ float    acc[3 * 4096];     // 48 KB: [c][ly*64+lx]
    __shared__ unsigned rs[64], re[64];

#pragma unroll
    for (int i = 0; i < 12; ++i) acc[i * 1024 + t] = 0.0f;
    if (t < 64) {
        const int blk = b * 64 + t;
        rs[t] = prefix[blk * (NBINS + 1) + tile];
        re[t] = prefix[blk * (NBINS + 1) + tile + 1];
    }
    __syncthreads();

    // 16 threads cooperate per source-block run
    const int chunk = t & 63;
    const int sub   = t >> 6;              // 0..15
    const unsigned s = rs[chunk], e = re[chunk];
    const float4* pbase = payload + (size_t)(b * 64 + chunk) * PTS_PER_BLOCK;
    for (unsigned i = s + sub; i < e; i += 16) {
        const float4 v = pbase[i];
        const unsigned idx = __float_as_uint(v.x) & 0xFFFu;
        atomicAdd(&acc[idx],        v.y);
        atomicAdd(&acc[4096 + idx], v.z);
        atomicAdd(&acc[8192 + idx], v.w);
    }
    __syncthreads();

    // fold corner partials (corner pixels received nothing from binning)
    const bool cx = (tx == 0) | (tx == 15);
    const bool cy = (ty == 0) | (ty == 15);
    if (cx & cy & (t < 3)) {
        const int ci = ((ty == 15) ? 2 : 0) + ((tx == 15) ? 1 : 0);
        float ssum = 0.0f;
        for (int ch = 0; ch < 64; ++ch)
            ssum += corner_out[(b * 64 + ch) * 12 + ci * 3 + t];
        const int cpix = ((ty == 15) ? 4032 : 0) + ((tx == 15) ? 63 : 0);
        acc[t * 4096 + cpix] += ssum;      // single writer per slot, post-barrier
    }
    __syncthreads();

    // dense clipped store: consecutive threads -> consecutive lx (256B runs)
    float* ob = out + (size_t)b * 3 * IMG_HW;
#pragma unroll
    for (int i = 0; i < 12; ++i) {
        const int lin = i * 1024 + t;
        const int c   = lin >> 12;
        const int pix = lin & 4095;
        const int ly  = pix >> 6, lx = pix & 63;
        float v = acc[lin];
        v = fminf(fmaxf(v, 0.0f), 1.0f);
        ob[(size_t)c * IMG_HW + (size_t)(ty * 64 + ly) * IMG_W + tx * 64 + lx] = v;
    }
}

extern "C" void kernel_launch(void* const* d_in, const int* in_sizes, int n_in,
                              void* d_out, int out_size, void* d_ws, size_t ws_size,
                              hipStream_t stream) {
    const float* uv  = (const float*)d_in[0];   // (4,14,512,512)
    const float* pos = (const float*)d_in[1];   // (4,3,512,512)
    float* out = (float*)d_out;                 // (4,3,1024,1024)

    float4*   payload    = (float4*)d_ws;                          // 16 MB
    unsigned* prefix     = (unsigned*)((char*)d_ws + PREFIX_OFF);  // 257 KB
    float*    corner_out = (float*)((char*)d_ws + CORNER_OFF);     // 12 KB

    // No memsets needed: prefix/corner fully written each call; payload is
    // only read within [prefix, prefix_next) ranges written this call.
    bin_kernel<<<K1_BLOCKS, 1024, 0, stream>>>(uv, pos, payload, prefix, corner_out);
    accum_kernel<<<BATCH * NBINS, 1024, 0, stream>>>(payload, prefix, corner_out, out);
}